// Round 16
// baseline (17.278 us; speedup 1.0000x reference)
//
#include <hip/hip_runtime.h>
#include <hip/hip_bf16.h>
#include <math.h>

// Problem: B=512, N=64, D=3, H=128.
// out[b,i,:] = sum_{j != i} g(dist_ij) * (pos[b,i,:] - pos[b,j,:])
// where g(d) = (MLP(features(d)) + b3) / max(d, 0.01).
// g depends ONLY on scalar dist -> tabulate g, lerp.
// Fine [0,2) x 8192 (delta 2.44e-4), coarse [0,16) x 4096.
// Build is latency-bound on per-block critical path (R15) -> 512-thread
// blocks: 8 waves/block (2 waves/SIMD), stage issue halved, the two
// 64-entry tiles computed in PARALLEL across waves (one 16-row MFMA tile
// per wave). 96 blocks x 128 entries.
// force_kernel: one block per batch, 16 (i,j) pairs per thread (R12 form).
// Fusion dead (4 variants: +24..+150us). rocprof per-dispatch has ~39us
// profiling floor -- only graph-replay dur_us A/B is trustworthy here.

#define NFINE   8192
#define NCOARSE 4096
#define ENTRIES 128
#define NBUILD  ((NFINE + NCOARSE) / ENTRIES)   // 96 builder blocks

typedef __attribute__((ext_vector_type(8))) short bf16x8;
typedef __attribute__((ext_vector_type(4))) float f32x4;
typedef __attribute__((ext_vector_type(8))) unsigned short ushort8_t;

__device__ __forceinline__ float fast_tanh(float x) {
    float e = __expf(2.0f * x);
    return 1.0f - 2.0f * __builtin_amdgcn_rcpf(e + 1.0f);
}

__device__ __forceinline__ unsigned short f2bf(float x) {
    __hip_bfloat16 h = __float2bfloat16(x);
    return *reinterpret_cast<unsigned short*>(&h);
}

__global__ __launch_bounds__(512) void build_table(
    const float* __restrict__ W1, const float* __restrict__ b1,
    const float* __restrict__ W2, const float* __restrict__ b2,
    const float* __restrict__ W3, const float* __restrict__ b3,
    float* __restrict__ tabF, float* __restrict__ tabC) {
    __shared__ __attribute__((aligned(16))) float sW1[6 * 128];
    __shared__ __attribute__((aligned(16))) float sb1[128], sb2[128], sW3[128];
    __shared__ __attribute__((aligned(16))) unsigned short sW2T[128][136];  // 34816 B

    const int t = threadIdx.x;

    // ---- stage small weights ----
    if (t < 128) { sb1[t] = b1[t]; sb2[t] = b2[t]; sW3[t] = W3[t]; }
    for (int i = t; i < 768; i += 512) sW1[i] = W1[i];

    // ---- in-block W2 transpose: W2[k][n] fp32 -> sW2T[n][k] bf16 ----
    // thread: q = t&63 -> rows k=2q,2q+1; c = t>>6 (0..7) -> cols [c*16,+16).
    // 8 float4 loads + 16 ds_write_b32 per thread (half of the 256-thread map).
    {
        int q = t & 63, c = t >> 6;
        const float* r0 = W2 + (2 * q) * 128 + c * 16;
        const float* r1 = r0 + 128;
#pragma unroll
        for (int m = 0; m < 4; ++m) {
            float4 a = *reinterpret_cast<const float4*>(r0 + 4 * m);
            float4 b = *reinterpret_cast<const float4*>(r1 + 4 * m);
            int n = c * 16 + 4 * m;
            // per-instruction lane addr differs only in q -> bank 2-way, free
            *reinterpret_cast<ushort2*>(&sW2T[n + 0][2 * q]) = make_ushort2(f2bf(a.x), f2bf(b.x));
            *reinterpret_cast<ushort2*>(&sW2T[n + 1][2 * q]) = make_ushort2(f2bf(a.y), f2bf(b.y));
            *reinterpret_cast<ushort2*>(&sW2T[n + 2][2 * q]) = make_ushort2(f2bf(a.z), f2bf(b.z));
            *reinterpret_cast<ushort2*>(&sW2T[n + 3][2 * q]) = make_ushort2(f2bf(a.w), f2bf(b.w));
        }
    }

    // block -> table segment (wave-uniform)
    int eb = blockIdx.x * ENTRIES;
    float dd; float* tp; int lo;
    if (eb < NFINE) { dd = 2.0f / (float)NFINE;    tp = tabF; lo = eb; }
    else            { dd = 16.0f / (float)NCOARSE; tp = tabC; lo = eb - NFINE; }

    const int w  = t >> 6;    // wave 0..7 -> entry rows w*16..w*16+15
    const int l  = t & 63;
    const int lg = l >> 4;    // k-group
    const int lr = l & 15;    // A-row / B-col within tile

    // thread's table entry (== its A-fragment row)
    const int e = w * 16 + lr;
    float d = (float)(lo + e) * dd;
    float inv_r = 1.0f / fmaxf(d, 0.5f);
    float inv2  = inv_r * inv_r;
    float inv6  = inv2 * inv2 * inv2;
    float inv12 = inv6 * inv6;
    float ft[6] = {d, inv_r, inv6, inv12, inv6 * inv_r, inv12 * inv_r};

    __syncthreads();

    // ---- layer-1 for exactly this thread's A-frag elements ----
    // A-frag (16x16x32): lane holds row lr, k = kt*32 + lg*8 + j.
    bf16x8 afr[4];
#pragma unroll
    for (int kt = 0; kt < 4; ++kt) {
        int c0 = kt * 32 + lg * 8;
        float ac[8], wv[8];
        *reinterpret_cast<float4*>(&ac[0]) = *reinterpret_cast<const float4*>(&sb1[c0]);
        *reinterpret_cast<float4*>(&ac[4]) = *reinterpret_cast<const float4*>(&sb1[c0 + 4]);
#pragma unroll
        for (int k = 0; k < 6; ++k) {
            *reinterpret_cast<float4*>(&wv[0]) = *reinterpret_cast<const float4*>(&sW1[k * 128 + c0]);
            *reinterpret_cast<float4*>(&wv[4]) = *reinterpret_cast<const float4*>(&sW1[k * 128 + c0 + 4]);
#pragma unroll
            for (int j = 0; j < 8; ++j) ac[j] = fmaf(ft[k], wv[j], ac[j]);
        }
        ushort8_t pk;
#pragma unroll
        for (int j = 0; j < 8; ++j) pk[j] = f2bf(fast_tanh(ac[j]));
        afr[kt] = *reinterpret_cast<bf16x8*>(&pk);
    }

    // ---- MFMA layer2 + fused tanh/W3 epilogue (one 16-row tile per wave) --
    {
        float part[4] = {0.f, 0.f, 0.f, 0.f};
        float b3v = b3[0];
#pragma unroll
        for (int nt = 0; nt < 8; ++nt) {
            f32x4 acc = {0.f, 0.f, 0.f, 0.f};
#pragma unroll
            for (int kt = 0; kt < 4; ++kt) {
                bf16x8 bfr = *reinterpret_cast<const bf16x8*>(&sW2T[nt * 16 + lr][kt * 32 + lg * 8]);
                acc = __builtin_amdgcn_mfma_f32_16x16x32_bf16(afr[kt], bfr, acc, 0, 0, 0);
            }
            float b2v = sb2[nt * 16 + lr];
            float w3v = sW3[nt * 16 + lr];
#pragma unroll
            for (int r = 0; r < 4; ++r)
                part[r] = fmaf(fast_tanh(acc[r] + b2v), w3v, part[r]);
        }
#pragma unroll
        for (int s = 1; s < 16; s <<= 1) {
#pragma unroll
            for (int r = 0; r < 4; ++r) part[r] += __shfl_xor(part[r], s);
        }
        if (lr == 0) {
            int ebase = w * 16 + lg * 4;   // D row = (l>>4)*4 + r
#pragma unroll
            for (int r = 0; r < 4; ++r) {
                int ee = lo + ebase + r;
                float dr = (float)ee * dd;
                tp[ee] = (part[r] + b3v) / fmaxf(dr, 0.01f);
            }
        }
    }
}

// One block per batch b. Thread t: i = t>>2, j in [16*(t&3), 16*(t&3)+16).
__global__ __launch_bounds__(256) void force_kernel(
    const float* __restrict__ pos, const float* __restrict__ tabF,
    const float* __restrict__ tabC, float* __restrict__ out) {
    __shared__ float sp[192];
    int b = blockIdx.x;
    int t = threadIdx.x;
    if (t < 192) sp[t] = pos[b * 192 + t];
    __syncthreads();

    int i  = t >> 2;
    int j0 = (t & 3) * 16;
    float xi = sp[i * 3 + 0], yi = sp[i * 3 + 1], zi = sp[i * 3 + 2];
    float fx = 0.f, fy = 0.f, fz = 0.f;
#pragma unroll
    for (int jj = 0; jj < 16; ++jj) {
        int j = j0 + jj;
        float dx = xi - sp[j * 3 + 0];
        float dy = yi - sp[j * 3 + 1];
        float dz = zi - sp[j * 3 + 2];
        float sq = fmaf(dx, dx, fmaf(dy, dy, dz * dz));
        float dist = sqrtf(sq);

        bool fine = dist < 2.0f;
        const float* tb = fine ? tabF : tabC;
        float scale = fine ? ((float)NFINE / 2.0f) : ((float)NCOARSE / 16.0f);
        int tmax = fine ? NFINE : NCOARSE;
        float tpos = dist * scale;
        int i0 = min((int)tpos, tmax - 2);
        float fr = tpos - (float)i0;
        float g0 = tb[i0], g1 = tb[i0 + 1];
        float g = fmaf(fr, g1 - g0, g0);
        if (j == i) g = 0.0f;   // off-diagonal mask

        fx = fmaf(g, dx, fx);
        fy = fmaf(g, dy, fy);
        fz = fmaf(g, dz, fz);
    }
    // reduce the 4 j-quarters (lanes t, t^1, t^2 within the aligned 4-group)
    fx += __shfl_xor(fx, 1); fy += __shfl_xor(fy, 1); fz += __shfl_xor(fz, 1);
    fx += __shfl_xor(fx, 2); fy += __shfl_xor(fy, 2); fz += __shfl_xor(fz, 2);
    if ((t & 3) == 0) {
        int o = (b * 64 + i) * 3;
        out[o + 0] = fx;
        out[o + 1] = fy;
        out[o + 2] = fz;
    }
}

extern "C" void kernel_launch(void* const* d_in, const int* in_sizes, int n_in,
                              void* d_out, int out_size, void* d_ws, size_t ws_size,
                              hipStream_t stream) {
    const float* pos = (const float*)d_in[0];
    const float* W1  = (const float*)d_in[1];
    const float* b1  = (const float*)d_in[2];
    const float* W2  = (const float*)d_in[3];
    const float* b2  = (const float*)d_in[4];
    const float* W3  = (const float*)d_in[5];
    const float* b3  = (const float*)d_in[6];

    char* ws = (char*)d_ws;
    float* tabF = (float*)(ws);                               // 32 KiB
    float* tabC = (float*)(ws + (size_t)NFINE * 4);           // 16 KiB
    float* out = (float*)d_out;

    hipLaunchKernelGGL(build_table, dim3(NBUILD), dim3(512), 0, stream,
                       W1, b1, W2, b2, W3, b3, tabF, tabC);
    hipLaunchKernelGGL(force_kernel, dim3(512), dim3(256), 0, stream,
                       pos, tabF, tabC, out);
}

// Round 17
// 16.704 us; speedup vs baseline: 1.0344x; 1.0344x over previous
//
#include <hip/hip_runtime.h>
#include <hip/hip_bf16.h>
#include <math.h>

// Problem: B=512, N=64, D=3, H=128.
// out[b,i,:] = sum_{j != i} g(dist_ij) * (pos[b,i,:] - pos[b,j,:])
// where g(d) = (MLP(features(d)) + b3) / max(d, 0.01).
// g depends ONLY on scalar dist -> tabulate g, lerp.
// Fine [0,2) x 8192 (delta 2.44e-4), coarse [0,16) x 4096.
// == R15 configuration (measured optimum 16.74us) ==
//   build_table: 192 blocks x 64 entries x 256 threads (ONE tile/block --
//     min per-block latency path); in-block W2 transpose; bf16 MFMA layer2.
//   force_kernel: one block per batch, 16 (i,j) pairs per thread.
// Measured-dead alternatives (do NOT retry): fusion w/ grid.sync (+150us),
// atomic-RMW spin (+85), acquire-load spin (+100), fenceless sc1 (+24);
// 512-thread build (+0.5); pair-symmetric shfl force (+2.2); pair-packed
// table + 2x TLP force (+0.7). rocprof per-dispatch has ~39us profiling
// floor -- only graph-replay dur_us A/B is trustworthy on this harness.

#define NFINE   8192
#define NCOARSE 4096
#define ENTRIES 64
#define NBUILD  ((NFINE + NCOARSE) / ENTRIES)   // 192 builder blocks

typedef __attribute__((ext_vector_type(8))) short bf16x8;
typedef __attribute__((ext_vector_type(4))) float f32x4;
typedef __attribute__((ext_vector_type(8))) unsigned short ushort8_t;

__device__ __forceinline__ float fast_tanh(float x) {
    float e = __expf(2.0f * x);
    return 1.0f - 2.0f * __builtin_amdgcn_rcpf(e + 1.0f);
}

__device__ __forceinline__ unsigned short f2bf(float x) {
    __hip_bfloat16 h = __float2bfloat16(x);
    return *reinterpret_cast<unsigned short*>(&h);
}

__global__ __launch_bounds__(256) void build_table(
    const float* __restrict__ W1, const float* __restrict__ b1,
    const float* __restrict__ W2, const float* __restrict__ b2,
    const float* __restrict__ W3, const float* __restrict__ b3,
    float* __restrict__ tabF, float* __restrict__ tabC) {
    __shared__ __attribute__((aligned(16))) float sW1[6 * 128];
    __shared__ __attribute__((aligned(16))) float sb1[128], sb2[128], sW3[128];
    __shared__ __attribute__((aligned(16))) unsigned short sW2T[128][136];  // 34816 B

    const int t = threadIdx.x;

    // ---- stage small weights ----
    if (t < 128) { sb1[t] = b1[t]; sb2[t] = b2[t]; sW3[t] = W3[t]; }
    for (int i = t; i < 768; i += 256) sW1[i] = W1[i];

    // ---- in-block W2 transpose: W2[k][n] fp32 -> sW2T[n][k] bf16 ----
    // thread: q = t&63 -> rows k=2q,2q+1; c = t>>6 -> cols [c*32, c*32+32).
    {
        int q = t & 63, c = t >> 6;
        const float* r0 = W2 + (2 * q) * 128 + c * 32;
        const float* r1 = r0 + 128;
#pragma unroll
        for (int m = 0; m < 8; ++m) {
            float4 a = *reinterpret_cast<const float4*>(r0 + 4 * m);
            float4 b = *reinterpret_cast<const float4*>(r1 + 4 * m);
            int n = c * 32 + 4 * m;
            // per-instruction lane addr differs only in q -> bank 2-way, free
            *reinterpret_cast<ushort2*>(&sW2T[n + 0][2 * q]) = make_ushort2(f2bf(a.x), f2bf(b.x));
            *reinterpret_cast<ushort2*>(&sW2T[n + 1][2 * q]) = make_ushort2(f2bf(a.y), f2bf(b.y));
            *reinterpret_cast<ushort2*>(&sW2T[n + 2][2 * q]) = make_ushort2(f2bf(a.z), f2bf(b.z));
            *reinterpret_cast<ushort2*>(&sW2T[n + 3][2 * q]) = make_ushort2(f2bf(a.w), f2bf(b.w));
        }
    }

    // block -> table segment (wave-uniform)
    int eb = blockIdx.x * ENTRIES;
    float dd; float* tp; int lo;
    if (eb < NFINE) { dd = 2.0f / (float)NFINE;    tp = tabF; lo = eb; }
    else            { dd = 16.0f / (float)NCOARSE; tp = tabC; lo = eb - NFINE; }

    const int w  = t >> 6;    // wave -> m-tile rows w*16..w*16+15
    const int l  = t & 63;
    const int lg = l >> 4;    // k-group
    const int lr = l & 15;    // A-row / B-col within tile

    // thread's table entry (== its A-fragment row)
    const int e = w * 16 + lr;
    float d = (float)(lo + e) * dd;
    float inv_r = 1.0f / fmaxf(d, 0.5f);
    float inv2  = inv_r * inv_r;
    float inv6  = inv2 * inv2 * inv2;
    float inv12 = inv6 * inv6;
    float ft[6] = {d, inv_r, inv6, inv12, inv6 * inv_r, inv12 * inv_r};

    __syncthreads();

    // ---- layer-1 for exactly this thread's A-frag elements ----
    // A-frag (16x16x32): lane holds row lr, k = kt*32 + lg*8 + j.
    bf16x8 afr[4];
#pragma unroll
    for (int kt = 0; kt < 4; ++kt) {
        int c0 = kt * 32 + lg * 8;
        float ac[8], wv[8];
        *reinterpret_cast<float4*>(&ac[0]) = *reinterpret_cast<const float4*>(&sb1[c0]);
        *reinterpret_cast<float4*>(&ac[4]) = *reinterpret_cast<const float4*>(&sb1[c0 + 4]);
#pragma unroll
        for (int k = 0; k < 6; ++k) {
            *reinterpret_cast<float4*>(&wv[0]) = *reinterpret_cast<const float4*>(&sW1[k * 128 + c0]);
            *reinterpret_cast<float4*>(&wv[4]) = *reinterpret_cast<const float4*>(&sW1[k * 128 + c0 + 4]);
#pragma unroll
            for (int j = 0; j < 8; ++j) ac[j] = fmaf(ft[k], wv[j], ac[j]);
        }
        ushort8_t pk;
#pragma unroll
        for (int j = 0; j < 8; ++j) pk[j] = f2bf(fast_tanh(ac[j]));
        afr[kt] = *reinterpret_cast<bf16x8*>(&pk);
    }

    // ---- MFMA layer2 + fused tanh/W3 epilogue ----
    {
        float part[4] = {0.f, 0.f, 0.f, 0.f};
        float b3v = b3[0];
#pragma unroll
        for (int nt = 0; nt < 8; ++nt) {
            f32x4 acc = {0.f, 0.f, 0.f, 0.f};
#pragma unroll
            for (int kt = 0; kt < 4; ++kt) {
                bf16x8 bfr = *reinterpret_cast<const bf16x8*>(&sW2T[nt * 16 + lr][kt * 32 + lg * 8]);
                acc = __builtin_amdgcn_mfma_f32_16x16x32_bf16(afr[kt], bfr, acc, 0, 0, 0);
            }
            float b2v = sb2[nt * 16 + lr];
            float w3v = sW3[nt * 16 + lr];
#pragma unroll
            for (int r = 0; r < 4; ++r)
                part[r] = fmaf(fast_tanh(acc[r] + b2v), w3v, part[r]);
        }
#pragma unroll
        for (int s = 1; s < 16; s <<= 1) {
#pragma unroll
            for (int r = 0; r < 4; ++r) part[r] += __shfl_xor(part[r], s);
        }
        if (lr == 0) {
            int ebase = w * 16 + lg * 4;   // D row = (l>>4)*4 + r
#pragma unroll
            for (int r = 0; r < 4; ++r) {
                int ee = lo + ebase + r;
                float dr = (float)ee * dd;
                tp[ee] = (part[r] + b3v) / fmaxf(dr, 0.01f);
            }
        }
    }
}

// One block per batch b. Thread t: i = t>>2, j in [16*(t&3), 16*(t&3)+16).
__global__ __launch_bounds__(256) void force_kernel(
    const float* __restrict__ pos, const float* __restrict__ tabF,
    const float* __restrict__ tabC, float* __restrict__ out) {
    __shared__ float sp[192];
    int b = blockIdx.x;
    int t = threadIdx.x;
    if (t < 192) sp[t] = pos[b * 192 + t];
    __syncthreads();

    int i  = t >> 2;
    int j0 = (t & 3) * 16;
    float xi = sp[i * 3 + 0], yi = sp[i * 3 + 1], zi = sp[i * 3 + 2];
    float fx = 0.f, fy = 0.f, fz = 0.f;
#pragma unroll
    for (int jj = 0; jj < 16; ++jj) {
        int j = j0 + jj;
        float dx = xi - sp[j * 3 + 0];
        float dy = yi - sp[j * 3 + 1];
        float dz = zi - sp[j * 3 + 2];
        float sq = fmaf(dx, dx, fmaf(dy, dy, dz * dz));
        float dist = sqrtf(sq);

        bool fine = dist < 2.0f;
        const float* tb = fine ? tabF : tabC;
        float scale = fine ? ((float)NFINE / 2.0f) : ((float)NCOARSE / 16.0f);
        int tmax = fine ? NFINE : NCOARSE;
        float tpos = dist * scale;
        int i0 = min((int)tpos, tmax - 2);
        float fr = tpos - (float)i0;
        float g0 = tb[i0], g1 = tb[i0 + 1];
        float g = fmaf(fr, g1 - g0, g0);
        if (j == i) g = 0.0f;   // off-diagonal mask

        fx = fmaf(g, dx, fx);
        fy = fmaf(g, dy, fy);
        fz = fmaf(g, dz, fz);
    }
    // reduce the 4 j-quarters (lanes t, t^1, t^2 within the aligned 4-group)
    fx += __shfl_xor(fx, 1); fy += __shfl_xor(fy, 1); fz += __shfl_xor(fz, 1);
    fx += __shfl_xor(fx, 2); fy += __shfl_xor(fy, 2); fz += __shfl_xor(fz, 2);
    if ((t & 3) == 0) {
        int o = (b * 64 + i) * 3;
        out[o + 0] = fx;
        out[o + 1] = fy;
        out[o + 2] = fz;
    }
}

extern "C" void kernel_launch(void* const* d_in, const int* in_sizes, int n_in,
                              void* d_out, int out_size, void* d_ws, size_t ws_size,
                              hipStream_t stream) {
    const float* pos = (const float*)d_in[0];
    const float* W1  = (const float*)d_in[1];
    const float* b1  = (const float*)d_in[2];
    const float* W2  = (const float*)d_in[3];
    const float* b2  = (const float*)d_in[4];
    const float* W3  = (const float*)d_in[5];
    const float* b3  = (const float*)d_in[6];

    char* ws = (char*)d_ws;
    float* tabF = (float*)(ws);                               // 32 KiB
    float* tabC = (float*)(ws + (size_t)NFINE * 4);           // 16 KiB
    float* out = (float*)d_out;

    hipLaunchKernelGGL(build_table, dim3(NBUILD), dim3(256), 0, stream,
                       W1, b1, W2, b2, W3, b3, tabF, tabC);
    hipLaunchKernelGGL(force_kernel, dim3(512), dim3(256), 0, stream,
                       pos, tabF, tabC, out);
}